// Round 4
// baseline (224.059 us; speedup 1.0000x reference)
//
#include <hip/hip_runtime.h>
#include <cmath>

typedef unsigned short u16;
typedef unsigned int u32;
typedef __bf16 bf16x2 __attribute__((ext_vector_type(2)));
typedef __bf16 bf16x8 __attribute__((ext_vector_type(8)));
typedef float f32x4 __attribute__((ext_vector_type(4)));
typedef float f32x16 __attribute__((ext_vector_type(16)));

#define NQ (768*768)
#define NK (384*768)

// ---------- helpers ----------
__device__ __forceinline__ u16 f2bf(float f) {
  u32 u = __float_as_uint(f);
  u32 r = (u + 0x7FFFu + ((u >> 16) & 1u)) >> 16;  // RNE
  return (u16)r;
}
__device__ __forceinline__ u32 packbf(float a, float b) {
#if __has_builtin(__builtin_amdgcn_cvt_pk_bf16_f32)
  bf16x2 v = __builtin_amdgcn_cvt_pk_bf16_f32(a, b);
  u32 r; __builtin_memcpy(&r, &v, 4); return r;
#else
  return (u32)f2bf(a) | ((u32)f2bf(b) << 16);
#endif
}
__device__ __forceinline__ float fexp2(float x) {
#if __has_builtin(__builtin_amdgcn_exp2f)
  return __builtin_amdgcn_exp2f(x);
#else
  return exp2f(x);
#endif
}
__device__ __forceinline__ bf16x8 ldfrag(const u16* p) { bf16x8 v; __builtin_memcpy(&v, p, 16); return v; }
__device__ __forceinline__ f32x16 mfma32_(bf16x8 a, bf16x8 b, f32x16 c) {
  return __builtin_amdgcn_mfma_f32_32x32x16_bf16(a, b, c, 0, 0, 0);
}

// ---------- 1) sum(|w|) per matrix ----------
__global__ __launch_bounds__(256) void abssum_kernel(const float* __restrict__ wq, const float* __restrict__ wk,
                                                     const float* __restrict__ wv, const float* __restrict__ wo,
                                                     float* __restrict__ sums) {
  int which = blockIdx.y;
  const float* w = (which == 0) ? wq : (which == 1) ? wk : (which == 2) ? wv : wo;
  int n4 = ((which == 0 || which == 3) ? NQ : NK) >> 2;
  const float4* w4 = (const float4*)w;
  float s = 0.f;
  for (int i = blockIdx.x * blockDim.x + threadIdx.x; i < n4; i += gridDim.x * blockDim.x) {
    float4 v = w4[i];
    s += fabsf(v.x) + fabsf(v.y) + fabsf(v.z) + fabsf(v.w);
  }
  for (int off = 32; off; off >>= 1) s += __shfl_down(s, off);
  __shared__ float ls[4];
  if ((threadIdx.x & 63) == 0) ls[threadIdx.x >> 6] = s;
  __syncthreads();
  if (threadIdx.x == 0) atomicAdd(&sums[which], ls[0] + ls[1] + ls[2] + ls[3]);
}

// ---------- 2) ternary quantize to bf16 {-1,0,1} ----------
__global__ __launch_bounds__(256) void quant_kernel(const float* __restrict__ wq, const float* __restrict__ wk,
                                                    const float* __restrict__ wv, const float* __restrict__ wo,
                                                    const float* __restrict__ sums,
                                                    u16* __restrict__ qw, u16* __restrict__ woq) {
  float thr0 = 0.7f * sums[0] * (1.f / NQ);
  float thr1 = 0.7f * sums[1] * (1.f / NK);
  float thr2 = 0.7f * sums[2] * (1.f / NK);
  float thr3 = 0.7f * sums[3] * (1.f / NQ);
  const int NQKV = NQ + 2 * NK;
  const int total = NQKV + NQ;
  for (int i = blockIdx.x * blockDim.x + threadIdx.x; i < total; i += gridDim.x * blockDim.x) {
    float v, th; u16* dst;
    if (i < NQ)            { v = wq[i];            th = thr0; dst = &qw[i]; }
    else if (i < NQ + NK)  { v = wk[i - NQ];       th = thr1; dst = &qw[i]; }
    else if (i < NQKV)     { v = wv[i - NQ - NK];  th = thr2; dst = &qw[i]; }
    else                   { v = wo[i - NQKV];     th = thr3; dst = &woq[i - NQKV]; }
    float q = (fabsf(v) >= th) ? ((v > 0.f) ? 1.f : -1.f) : 0.f;
    *dst = f2bf(q);
  }
}

// ---------- 3) x -> bf16 ----------
__global__ __launch_bounds__(256) void castx_kernel(const float* __restrict__ x, u16* __restrict__ xb) {
  int i = blockIdx.x * blockDim.x + threadIdx.x;
  float4 v = ((const float4*)x)[i];
  u16 o[4] = { f2bf(v.x), f2bf(v.y), f2bf(v.z), f2bf(v.w) };
  __builtin_memcpy(&xb[i * 4], o, 8);
}

// ---------- shared GEMM core: C[64m x 128n] += A[m][k] * B[n][k], K=768 ----------
// 4 waves: wm = w&1 (32 rows), wn = w>>1 (64 cols = 2 n-blocks).
// B staged via global_load_lds into Bt: 1024 16B-chunks per k0-step (rd=0..3 x 4 waves x 64 lanes),
// chunk-in-row xor-swizzle (jp = jl ^ (n&7)). A-frags read directly from global (L2-resident).
__device__ __forceinline__ void gemm_tile_64x128(const u16* __restrict__ A, const u16* __restrict__ Bw,
                                                 u16* Bt, int tm, int tn, f32x16 acc[2]) {
  int t = threadIdx.x, lane = t & 63, w = t >> 6, c = lane & 31, g2 = lane >> 5;
  int wm = w & 1, wn = w >> 1;
  const u16* arow = A + (tm * 64 + wm * 32 + c) * 768;
  for (int k0 = 0; k0 < 768; k0 += 64) {
#pragma unroll
    for (int rd = 0; rd < 4; rd++) {
      int ch = (rd * 4 + w) * 64 + lane;          // 16B chunk index in [0,1024)
      int n = ch >> 3, jp = ch & 7;
      int jl = jp ^ (n & 7);                      // logical k-chunk for this physical slot
      const u16* gp = Bw + (tn * 128 + n) * 768 + k0 + jl * 8;
      __builtin_amdgcn_global_load_lds((const __attribute__((address_space(1))) u32*)gp,
                                       (__attribute__((address_space(3))) u32*)(Bt + (rd * 4 + w) * 512),
                                       16, 0, 0);
    }
    bf16x8 af[4];
#pragma unroll
    for (int ks = 0; ks < 4; ks++) af[ks] = ldfrag(arow + k0 + ks * 16 + g2 * 8);
    __syncthreads();
#pragma unroll
    for (int ks = 0; ks < 4; ks++) {
#pragma unroll
      for (int nb = 0; nb < 2; nb++) {
        int n = wn * 64 + nb * 32 + c;
        int jp = (ks * 2 + g2) ^ (n & 7);
        bf16x8 bf = ldfrag(Bt + n * 64 + jp * 8);
        acc[nb] = mfma32_(af[ks], bf, acc[nb]);
      }
    }
    __syncthreads();
  }
}

// ---------- 4) fused QKV GEMM + scale + RoPE + permuted-V transpose ----------
// N layout: tn 0..5 = Q (head = 2tn+wn), 6..8 = K (kvh = 2(tn-6)+wn), 9..11 = V (kvh = 2(tn-9)+wn).
// Q additionally scaled by 0.125*log2(e) so attention uses raw exp2.
// vT stored with key index bits 2<->3 swapped so attn's PV A-frag needs no lane exchange.
__global__ __launch_bounds__(256, 4) void gemm_qkv_kernel(const u16* __restrict__ xb, const u16* __restrict__ qw,
                                                          const float* __restrict__ sums,
                                                          u16* __restrict__ qb, u16* __restrict__ kb,
                                                          u16* __restrict__ vT) {
  __shared__ u16 Bt[8192];
  int tn = blockIdx.x, tm = blockIdx.y;
  f32x16 acc[2]; acc[0] = (f32x16)0.f; acc[1] = (f32x16)0.f;
  gemm_tile_64x128(xb, qw, Bt, tm, tn, acc);
  int t = threadIdx.x, lane = t & 63, w = t >> 6, c = lane & 31, g2 = lane >> 5;
  int wm = w & 1, wn = w >> 1;
  float sq = sums[0] * (1.f / NQ) * 0.180336880111120f;  // * 0.125 * log2(e)
  float sk = sums[1] * (1.f / NK);
  float sv = sums[2] * (1.f / NK);
  int mb = tm * 64 + wm * 32 + 4 * g2;
  if (tn < 9) {
    float sc = (tn < 6) ? sq : sk;
    u16* outp = (tn < 6) ? qb : kb;
    int head = (tn < 6) ? (tn * 2 + wn) : ((tn - 6) * 2 + wn);
    int stride = (tn < 6) ? 768 : 384;
    float f = fexp2((float)c * -0.41524101186092029f);   // 10000^(-c/32)
#pragma unroll
    for (int r = 0; r < 16; r++) {
      int m = mb + (r & 3) + 8 * (r >> 2);
      int s = m & 2047;
      float sn, cs; sincosf((float)s * f, &sn, &cs);
      float x1 = acc[0][r] * sc, x2 = acc[1][r] * sc;
      outp[m * stride + head * 64 + c]      = f2bf(x1 * cs - x2 * sn);
      outp[m * stride + head * 64 + c + 32] = f2bf(x2 * cs + x1 * sn);
    }
  } else {
    int kvh = (tn - 9) * 2 + wn;
#pragma unroll
    for (int nb = 0; nb < 2; nb++)
#pragma unroll
      for (int r = 0; r < 16; r++) {
        int m = mb + (r & 3) + 8 * (r >> 2);
        int bb = m >> 11, s = m & 2047;
        int sp = (s & ~12) | ((s & 4) << 1) | ((s & 8) >> 1);   // swap bits 2,3
        vT[((bb * 6 + kvh) * 64 + nb * 32 + c) * 2048 + sp] = f2bf(acc[nb][r] * sv);
      }
  }
}

// ---------- 5) attention: LDS-free barrier-free main loop, no cross-lane exchange ----------
// grid (32 q-tiles of 64 rows, 24 b*h). block 256 = 4 waves; wave w: keys [w*512, w*512+512).
// S^T = K Q^T (C cols = q). vT's key permutation makes exp2(S) registers directly the PV A-frags.
__global__ __launch_bounds__(256, 3) void attn_kernel(const u16* __restrict__ qb, const u16* __restrict__ kb,
                                                      const u16* __restrict__ vT, u16* __restrict__ ab) {
  __shared__ float Obuf[4][32][66];
  __shared__ float Lbuf[4][64];
  int qt = blockIdx.x, bh = blockIdx.y;
  int b = bh / 12, h = bh % 12, kvh = h >> 1;
  int t = threadIdx.x, lane = t & 63, w = t >> 6, c = lane & 31, g2 = lane >> 5;

  const u16* qbase = qb + (b * 2048 + qt * 64) * 768 + h * 64;
  bf16x8 qf[2][4];
#pragma unroll
  for (int qn = 0; qn < 2; qn++)
#pragma unroll
    for (int ks = 0; ks < 4; ks++)
      qf[qn][ks] = ldfrag(qbase + (qn * 32 + c) * 768 + ks * 16 + 8 * g2);

  f32x16 fz = (f32x16)0.f;
  f32x16 O[2][2] = {{fz, fz}, {fz, fz}};   // [qn][dn]
  float lsum[2] = {0.f, 0.f};

  const u16* kbase = kb + (b * 2048) * 384 + kvh * 64;
  const u16* vbase = vT + ((b * 6 + kvh) * 64) * 2048;

  for (int it = 0; it < 8; it++) {
    int key0 = w * 512 + it * 64;
    bf16x8 kf[2][4];
#pragma unroll
    for (int km = 0; km < 2; km++)
#pragma unroll
      for (int ks = 0; ks < 4; ks++)
        kf[km][ks] = ldfrag(kbase + (key0 + km * 32 + c) * 384 + ks * 16 + 8 * g2);
    f32x16 S[2][2] = {{fz, fz}, {fz, fz}};
#pragma unroll
    for (int ks = 0; ks < 4; ks++)
#pragma unroll
      for (int km = 0; km < 2; km++)
#pragma unroll
        for (int qn = 0; qn < 2; qn++)
          S[km][qn] = mfma32_(kf[km][ks], qf[qn][ks], S[km][qn]);
    bf16x8 vf[2][4];
#pragma unroll
    for (int dn = 0; dn < 2; dn++)
#pragma unroll
      for (int ks = 0; ks < 4; ks++)
        vf[dn][ks] = ldfrag(vbase + (dn * 32 + c) * 2048 + key0 + ks * 16 + 8 * g2);
    // exp2 -> pack: registers ARE the PV A-frags (vT key-permuted to match C-layout ownership)
    bf16x8 PA[2][4];
#pragma unroll
    for (int qn = 0; qn < 2; qn++) {
#pragma unroll
      for (int km = 0; km < 2; km++) {
        float e[16];
#pragma unroll
        for (int r = 0; r < 16; r++) {
          e[r] = fexp2(S[km][qn][r]);
          lsum[qn] += e[r];
        }
        u32 P[8];
#pragma unroll
        for (int j = 0; j < 8; j++) P[j] = packbf(e[2 * j], e[2 * j + 1]);
        __builtin_memcpy(&PA[qn][km * 2 + 0], &P[0], 16);
        __builtin_memcpy(&PA[qn][km * 2 + 1], &P[4], 16);
      }
    }
#pragma unroll
    for (int ks = 0; ks < 4; ks++)
#pragma unroll
      for (int qn = 0; qn < 2; qn++)
#pragma unroll
        for (int dn = 0; dn < 2; dn++)
          O[qn][dn] = mfma32_(PA[qn][ks], vf[dn][ks], O[qn][dn]);
  }
#pragma unroll
  for (int qn = 0; qn < 2; qn++) lsum[qn] += __shfl_xor(lsum[qn], 32);
  if (g2 == 0) { Lbuf[w][c] = lsum[0]; Lbuf[w][32 + c] = lsum[1]; }
  // two-phase combine (halves LDS vs single-phase)
#pragma unroll
  for (int qn = 0; qn < 2; qn++) {
    if (qn) __syncthreads();
#pragma unroll
    for (int dn = 0; dn < 2; dn++)
#pragma unroll
      for (int r = 0; r < 16; r++) {
        int qq = (r & 3) + 8 * (r >> 2) + 4 * g2;
        Obuf[w][qq][dn * 32 + c] = O[qn][dn][r];
      }
    __syncthreads();
    int qq = t >> 3, dc = (t & 7) * 8;
    float l = Lbuf[0][qn * 32 + qq] + Lbuf[1][qn * 32 + qq] + Lbuf[2][qn * 32 + qq] + Lbuf[3][qn * 32 + qq];
    float inv = 1.f / l;
    u16 o[8];
#pragma unroll
    for (int j = 0; j < 8; j++) {
      float s = Obuf[0][qq][dc + j] + Obuf[1][qq][dc + j] + Obuf[2][qq][dc + j] + Obuf[3][qq][dc + j];
      o[j] = f2bf(s * inv);
    }
    __builtin_memcpy(ab + (b * 2048 + qt * 64 + qn * 32 + qq) * 768 + h * 64 + dc, o, 16);
  }
}

// ---------- 6) output projection GEMM -> fp32 ----------
__global__ __launch_bounds__(256, 4) void gemm_out_kernel(const u16* __restrict__ ab, const u16* __restrict__ woq,
                                                          const float* __restrict__ sums, float* __restrict__ out) {
  __shared__ u16 Bt[8192];
  int tn = blockIdx.x, tm = blockIdx.y;
  f32x16 acc[2]; acc[0] = (f32x16)0.f; acc[1] = (f32x16)0.f;
  gemm_tile_64x128(ab, woq, Bt, tm, tn, acc);
  int t = threadIdx.x, lane = t & 63, w = t >> 6, c = lane & 31, g2 = lane >> 5;
  int wm = w & 1, wn = w >> 1;
  float so = sums[3] * (1.f / NQ);
  int mb = tm * 64 + wm * 32 + 4 * g2;
#pragma unroll
  for (int nb = 0; nb < 2; nb++)
#pragma unroll
    for (int r = 0; r < 16; r++) {
      int m = mb + (r & 3) + 8 * (r >> 2);
      out[m * 768 + tn * 128 + wn * 64 + nb * 32 + c] = acc[nb][r] * so;
    }
}

// ---------- launch ----------
extern "C" void kernel_launch(void* const* d_in, const int* in_sizes, int n_in,
                              void* d_out, int out_size, void* d_ws, size_t ws_size,
                              hipStream_t stream) {
  const float* x  = (const float*)d_in[0];
  const float* wq = (const float*)d_in[1];
  const float* wk = (const float*)d_in[2];
  const float* wv = (const float*)d_in[3];
  const float* wo = (const float*)d_in[4];
  float* out = (float*)d_out;
  char* ws = (char*)d_ws;

  float* sums = (float*)ws;                    // 16 B
  u16* qw  = (u16*)(ws + 256);                 // [1536][768]
  u16* woq = (u16*)(ws + 2359552);             // [768][768]
  u16* xb  = (u16*)(ws + 3539200);             // [4096][768]
  u16* qb  = (u16*)(ws + 9830656);             // [4096][768]
  u16* kb  = (u16*)(ws + 16122112);            // [4096][384]
  u16* vT  = (u16*)(ws + 19267840);            // [2*6][64][2048] (key-permuted)
  u16* ab  = (u16*)(ws + 22413568);            // [4096][768]

  hipMemsetAsync(sums, 0, 16, stream);
  dim3 blk(256);
  abssum_kernel<<<dim3(64, 4), blk, 0, stream>>>(wq, wk, wv, wo, sums);
  quant_kernel<<<dim3(6912), blk, 0, stream>>>(wq, wk, wv, wo, sums, qw, woq);
  castx_kernel<<<dim3(3072), blk, 0, stream>>>(x, xb);
  gemm_qkv_kernel<<<dim3(12, 64), blk, 0, stream>>>(xb, qw, sums, qb, kb, vT);
  attn_kernel<<<dim3(32, 24), blk, 0, stream>>>(qb, kb, vT, ab);
  gemm_out_kernel<<<dim3(6, 64), blk, 0, stream>>>(ab, woq, sums, out);
}